// Round 12
// baseline (375.164 us; speedup 1.0000x reference)
//
#include <hip/hip_runtime.h>

#define TPB 256
#define N_RELS 64
#define EPT 4
#define LOG2E 1.4426950408889634f

typedef float f4 __attribute__((ext_vector_type(4)));
typedef int   i4 __attribute__((ext_vector_type(4)));

// one group = 4 edges: 1 int4 + 6 float4 loads
struct G { i4 R; f4 P0, P1, P2, C0, C1, C2; };

__device__ __forceinline__ void load_group(G& g, const int* __restrict__ rels,
                                           const float* __restrict__ prnt,
                                           const float* __restrict__ child, int idx) {
    g.R  = ((const i4*)rels)[idx];
    const f4* p = (const f4*)prnt  + (size_t)idx * 3;
    const f4* c = (const f4*)child + (size_t)idx * 3;
    g.P0 = p[0]; g.P1 = p[1]; g.P2 = p[2];
    g.C0 = c[0]; g.C1 = c[1]; g.C2 = c[2];
}

// sMB4: [N_RELS][3] float4 per rel = [M*log2e (9) | beta (3)]
__device__ __forceinline__ void edge_compute(const f4* __restrict__ sMB4, int r,
    float p0, float p1, float p2, float c0, float c1, float c2,
    float zeps, float sf2, float* __restrict__ o)
{
    const f4* mb = sMB4 + r * 3;
    f4 q0 = mb[0], q1 = mb[1], q2 = mb[2];   // 3x ds_read_b128

    // scores pre-scaled by log2e (folded into staged M) -> raw v_exp_f32
    float s0 = q0.x * c0 + q0.y * c1 + q0.z * c2;
    float s1 = q0.w * c0 + q1.x * c1 + q1.y * c2;
    float s2 = q1.z * c0 + q1.w * c1 + q2.x * c2;
    float e0 = __builtin_amdgcn_exp2f(s0);   // |s|<=~15 in log2 space: f32-safe, no max-sub
    float e1 = __builtin_amdgcn_exp2f(s1);
    float e2 = __builtin_amdgcn_exp2f(s2);
    float inv = __builtin_amdgcn_rcpf(e0 + e1 + e2);
    float ch0 = e0 * inv, ch1 = e1 * inv, ch2 = e2 * inv;

    // alpha = p + b*(ch-p)
    float a0 = p0 + q2.y * (ch0 - p0);
    float a1 = p1 + q2.z * (ch1 - p1);
    float a2 = p2 + q2.w * (ch2 - p2);

    // entropy in log2 space; 1/ln2 folded into sf2
    float z0 = fmaxf(zeps, p0 + ch0);
    float z1 = fmaxf(zeps, p1 + ch1);
    float z2 = fmaxf(zeps, p2 + ch2);
    float zinv = __builtin_amdgcn_rcpf(z0 + z1 + z2);
    float zn0 = z0 * zinv, zn1 = z1 * zinv, zn2 = z2 * zinv;
    float ent2 = -(zn0 * __builtin_amdgcn_logf(zn0)
                 + zn1 * __builtin_amdgcn_logf(zn1)
                 + zn2 * __builtin_amdgcn_logf(zn2));

    // cosine similarity
    float dot = p0 * ch0 + p1 * ch1 + p2 * ch2;
    float np2 = p0 * p0 + p1 * p1 + p2 * p2;
    float nc2 = ch0 * ch0 + ch1 * ch1 + ch2 * ch2;
    float prod = np2 * nc2;
    float cosn = (prod > 0.0f) ? dot * __builtin_amdgcn_rsqf(prod) : dot;

    float scale = sf2 * (1.1f + cosn) * __builtin_amdgcn_rcpf(ent2);

    o[0] = a0 * scale;
    o[1] = a1 * scale;
    o[2] = a2 * scale;
}

__device__ __forceinline__ void compute_store(const G& g, const f4* __restrict__ sMB4,
    float zeps, float sf2, float* __restrict__ out, int idx)
{
    int   R[EPT] = {g.R.x, g.R.y, g.R.z, g.R.w};
    float P[12]  = {g.P0.x, g.P0.y, g.P0.z, g.P0.w, g.P1.x, g.P1.y, g.P1.z, g.P1.w,
                    g.P2.x, g.P2.y, g.P2.z, g.P2.w};
    float C[12]  = {g.C0.x, g.C0.y, g.C0.z, g.C0.w, g.C1.x, g.C1.y, g.C1.z, g.C1.w,
                    g.C2.x, g.C2.y, g.C2.z, g.C2.w};
    float O[12];
    #pragma unroll
    for (int e = 0; e < EPT; ++e)   // fully unrolled -> static indices, no scratch
        edge_compute(sMB4, R[e], P[3*e], P[3*e+1], P[3*e+2],
                     C[3*e], C[3*e+1], C[3*e+2], zeps, sf2, &O[3*e]);
    f4* o4 = (f4*)out + (size_t)idx * 3;
    const f4* Ov = (const f4*)O;
    o4[0] = Ov[0]; o4[1] = Ov[1]; o4[2] = Ov[2];
}

__global__ __launch_bounds__(TPB) void alpha_kernel(
    const float* __restrict__ prnt,
    const float* __restrict__ child,
    const int*   __restrict__ rels,
    const float* __restrict__ M,
    const float* __restrict__ beta,
    const float* __restrict__ zeps_p,
    const float* __restrict__ sf_p,
    float* __restrict__ out,
    int n_groups,
    long n_edges)
{
    __shared__ f4 sMB4[N_RELS * 3];
    {
        float* sMB = (float*)sMB4;
        for (int i = threadIdx.x; i < N_RELS * 12; i += TPB) {
            int r = i / 12, j = i - r * 12;
            sMB[i] = (j < 9) ? M[r * 9 + j] * LOG2E : beta[r * 3 + (j - 9)];
        }
    }
    __syncthreads();

    const float zeps = *zeps_p;
    const float sf2  = *sf_p * LOG2E;   // folds 1/ln2 of the entropy

    const int nthreads = gridDim.x * TPB;
    const int tid0 = blockIdx.x * TPB + threadIdx.x;

    // depth-2 software pipeline over grid-stride groups: named ping-pong buffers
    int g = tid0;
    if (g < n_groups) {
        G A, B;
        load_group(A, rels, prnt, child, g);
        while (true) {
            int gn = g + nthreads;
            if (gn < n_groups) load_group(B, rels, prnt, child, gn);  // issue before compute
            compute_store(A, sMB4, zeps, sf2, out, g);
            if (gn >= n_groups) break;
            g = gn;
            gn = g + nthreads;
            if (gn < n_groups) load_group(A, rels, prnt, child, gn);
            compute_store(B, sMB4, zeps, sf2, out, g);
            if (gn >= n_groups) break;
            g = gn;
        }
    }

    // scalar tail (n_edges % EPT != 0 only)
    long eidx = (long)n_groups * EPT + (long)tid0;
    if (eidx < n_edges) {
        float o[3];
        edge_compute(sMB4, rels[eidx],
                     prnt[eidx * 3 + 0], prnt[eidx * 3 + 1], prnt[eidx * 3 + 2],
                     child[eidx * 3 + 0], child[eidx * 3 + 1], child[eidx * 3 + 2],
                     zeps, sf2, o);
        out[eidx * 3 + 0] = o[0];
        out[eidx * 3 + 1] = o[1];
        out[eidx * 3 + 2] = o[2];
    }
}

extern "C" void kernel_launch(void* const* d_in, const int* in_sizes, int n_in,
                              void* d_out, int out_size, void* d_ws, size_t ws_size,
                              hipStream_t stream) {
    // input order: var_sfx, prnt_probs, child_probs, rels, M, beta, z_epsilon, scale_factor
    const float* prnt  = (const float*)d_in[1];
    const float* child = (const float*)d_in[2];
    const int*   rels  = (const int*)d_in[3];
    const float* M     = (const float*)d_in[4];
    const float* beta  = (const float*)d_in[5];
    const float* zeps  = (const float*)d_in[6];
    const float* sf    = (const float*)d_in[7];
    float* out = (float*)d_out;

    long n_edges  = in_sizes[3];
    int  n_groups = (int)(n_edges / EPT);

    int blocks = 2048;   // 256 CU x 8 blocks: machine-filling persistent grid
    long need = ((long)n_groups + TPB - 1) / TPB;
    if (need < blocks) blocks = (int)(need > 0 ? need : 1);

    alpha_kernel<<<blocks, TPB, 0, stream>>>(prnt, child, rels, M, beta,
                                             zeps, sf, out, n_groups, n_edges);
}